// Round 1
// baseline (153.636 us; speedup 1.0000x reference)
//
#include <hip/hip_runtime.h>
#include <math.h>

// ---------------------------------------------------------------------------
// Problem constants (B=4, S=8192, D=1024, H=4, hd=256)
// Static lattice enumerated from the reference:
//   positions: 12, 36, 104, 304, 888, 2592, 7568
//   16 entries, level-major order:
//   L1: E0..E6  (one per pos, nodes = 3 ancestors, w=1)
//   L2: E7..E12, L3: E13..E15
// ---------------------------------------------------------------------------

#define SEQ 8192
#define DM  1024

__device__ __constant__ int c_nodes[16][3] = {
  {0,2,4},{2,4,12},{4,12,36},{12,36,104},{36,104,304},{104,304,888},{304,888,2592},
  {0,0,0},{0,2,0},{0,2,4},{2,4,12},{4,12,36},{12,36,104},
  {0,0,0},{0,2,0},{0,2,4}};
__device__ __constant__ float c_wt[16][3] = {
  {1,1,1},{1,1,1},{1,1,1},{1,1,1},{1,1,1},{1,1,1},{1,1,1},
  {1,0,0},{1,1,0},{1,1,1},{1,2,3},{1,2,3},{1,2,3},
  {1,0,0},{1,1,0},{1,1,1}};
__device__ __constant__ float c_winv[16] = {
  1.f/3.f,1.f/3.f,1.f/3.f,1.f/3.f,1.f/3.f,1.f/3.f,1.f/3.f,
  1.f,0.5f,1.f/3.f,1.f/6.f,1.f/6.f,1.f/6.f,
  1.f,0.5f,1.f/3.f};
__device__ __constant__ int c_pos[7]  = {12,36,104,304,888,2592,7568};
__device__ __constant__ int c_ne[7]   = {1,2,2,2,3,3,3};
__device__ __constant__ int c_posE[7][3] = {
  {0,0,0},{1,7,0},{2,8,0},{3,9,0},{4,10,13},{5,11,14},{6,12,15}};

// ---------------------------------------------------------------------------
// 1) out = x  (134 MB, the memory-bound floor)
// ---------------------------------------------------------------------------
__global__ __launch_bounds__(256) void k_copy(const float4* __restrict__ src,
                                              float4* __restrict__ dst, long n)
{
  long i = (long)blockIdx.x * 256 + threadIdx.x;
  long stride = (long)gridDim.x * 256;
  for (; i < n; i += stride) dst[i] = src[i];
}

// ---------------------------------------------------------------------------
// 2) F[e][b][:] = weighted mean of x rows; blocks >= 64 gather q rows into
//    QIN and COMB[:,1024:2048].
// ---------------------------------------------------------------------------
__global__ __launch_bounds__(256) void k_feats(const float* __restrict__ x,
                                               float* __restrict__ F,
                                               float* __restrict__ QIN,
                                               float* __restrict__ CB)
{
  int bx = blockIdx.x;
  int d  = threadIdx.x * 4;
  if (bx < 64) {
    int e = bx >> 2, b = bx & 3;
    float4 s = make_float4(0.f, 0.f, 0.f, 0.f);
#pragma unroll
    for (int n = 0; n < 3; ++n) {
      float w = c_wt[e][n];
      const float4 v = *(const float4*)(x + ((size_t)b * SEQ + c_nodes[e][n]) * DM + d);
      s.x += w * v.x; s.y += w * v.y; s.z += w * v.z; s.w += w * v.w;
    }
    float inv = c_winv[e];
    s.x *= inv; s.y *= inv; s.z *= inv; s.w *= inv;
    *(float4*)(F + (size_t)(e * 4 + b) * DM + d) = s;
  } else {
    int i = bx - 64;              // 0..27
    int p = i >> 2, b = i & 3;
    const float4 v = *(const float4*)(x + ((size_t)b * SEQ + c_pos[p]) * DM + d);
    *(float4*)(QIN + (size_t)i * DM + d) = v;
    *(float4*)(CB + (size_t)i * 2048 + 1024 + d) = v;
  }
}

// ---------------------------------------------------------------------------
// Generic rows-GEMM body: Y[r][j] = sum_k X[r][k]*W[j][k] + bias[j], j<1024.
// block=256 (4 waves), wave computes 4 j's for 16 rows; lanes over k (float4).
// grid.x = 64 (j tiles of 16), grid.y = row chunks of 16.
// ---------------------------------------------------------------------------
__device__ __forceinline__ void gemm_body(const float* __restrict__ X,
                                          const float* __restrict__ W,
                                          const float* __restrict__ Bv,
                                          float* __restrict__ Y,
                                          int R, int K, int ldy)
{
  int r0 = blockIdx.y * 16;
  if (r0 >= R) return;
  int lane = threadIdx.x & 63;
  int wv   = threadIdx.x >> 6;
  int jbase = blockIdx.x * 16 + wv * 4;

  float acc0[16], acc1[16], acc2[16], acc3[16];
#pragma unroll
  for (int r = 0; r < 16; ++r) { acc0[r]=0.f; acc1[r]=0.f; acc2[r]=0.f; acc3[r]=0.f; }

  const int T = K >> 8;               // k chunks of 256 (lane*4)
  for (int t = 0; t < T; ++t) {
    int k = t * 256 + lane * 4;
    const float4 w0 = *(const float4*)(W + (size_t)(jbase + 0) * K + k);
    const float4 w1 = *(const float4*)(W + (size_t)(jbase + 1) * K + k);
    const float4 w2 = *(const float4*)(W + (size_t)(jbase + 2) * K + k);
    const float4 w3 = *(const float4*)(W + (size_t)(jbase + 3) * K + k);
#pragma unroll
    for (int r = 0; r < 16; ++r) {
      const float4 xv = *(const float4*)(X + (size_t)(r0 + r) * K + k);
      acc0[r] += w0.x*xv.x + w0.y*xv.y + w0.z*xv.z + w0.w*xv.w;
      acc1[r] += w1.x*xv.x + w1.y*xv.y + w1.z*xv.z + w1.w*xv.w;
      acc2[r] += w2.x*xv.x + w2.y*xv.y + w2.z*xv.z + w2.w*xv.w;
      acc3[r] += w3.x*xv.x + w3.y*xv.y + w3.z*xv.z + w3.w*xv.w;
    }
  }
#pragma unroll
  for (int r = 0; r < 16; ++r) {
    float v0 = acc0[r], v1 = acc1[r], v2 = acc2[r], v3 = acc3[r];
#pragma unroll
    for (int off = 32; off >= 1; off >>= 1) {
      v0 += __shfl_xor(v0, off); v1 += __shfl_xor(v1, off);
      v2 += __shfl_xor(v2, off); v3 += __shfl_xor(v3, off);
    }
    acc0[r] = v0; acc1[r] = v1; acc2[r] = v2; acc3[r] = v3;
  }
  if (lane == 0) {
    float b0 = Bv[jbase + 0], b1 = Bv[jbase + 1], b2 = Bv[jbase + 2], b3 = Bv[jbase + 3];
#pragma unroll
    for (int r = 0; r < 16; ++r) {
      if (r0 + r < R) {
        float* yr = Y + (size_t)(r0 + r) * ldy + jbase;
        yr[0] = acc0[r] + b0; yr[1] = acc1[r] + b1;
        yr[2] = acc2[r] + b2; yr[3] = acc3[r] + b3;
      }
    }
  }
}

__global__ __launch_bounds__(256) void k_gemm(const float* __restrict__ X,
                                              const float* __restrict__ W,
                                              const float* __restrict__ Bv,
                                              float* __restrict__ Y,
                                              int R, int K, int ldy)
{
  gemm_body(X, W, Bv, Y, R, K, ldy);
}

// Lattice MLP matmul: grid.z = level (0..2); per-level row ranges in
// entry-major storage: L1 rows [0,28), L2 [28,52), L3 [52,64).
__global__ __launch_bounds__(256) void k_mm_lat(const float* __restrict__ X,
                                                const float* __restrict__ W,
                                                const float* __restrict__ Bv,
                                                float* __restrict__ Y)
{
  const int e0_[3] = {0, 7, 13};
  const int ne_[3] = {7, 6, 3};
  int z  = blockIdx.z;
  int rs = e0_[z] * 4;
  int R  = ne_[z] * 4;
  gemm_body(X + (size_t)rs * DM, W + (size_t)z * DM * DM, Bv + z * DM,
            Y + (size_t)rs * DM, R, DM, DM);
}

// Q/K/V projections: z=0 -> QH from QIN (R=28); z=1 -> KH from KV (R=64);
// z=2 -> VH from KV (R=64). attn_in_w rows [0,1024)/[1024,2048)/[2048,3072).
__global__ __launch_bounds__(256) void k_qkv(const float* __restrict__ QIN,
                                             const float* __restrict__ KV,
                                             const float* __restrict__ Wqkv,
                                             const float* __restrict__ Bqkv,
                                             float* __restrict__ QH,
                                             float* __restrict__ KH,
                                             float* __restrict__ VH)
{
  int z = blockIdx.z;
  if (z == 0)      gemm_body(QIN, Wqkv,                    Bqkv,        QH, 28, DM, DM);
  else if (z == 1) gemm_body(KV,  Wqkv + (size_t)DM * DM,  Bqkv + DM,   KH, 64, DM, DM);
  else             gemm_body(KV,  Wqkv + (size_t)2*DM*DM,  Bqkv + 2*DM, VH, 64, DM, DM);
}

// ---------------------------------------------------------------------------
// Block mean/var over 1024 elements (256 threads x 4), then user applies.
// ---------------------------------------------------------------------------
__device__ __forceinline__ void block_mv(float s, float q, float* mean, float* rstd)
{
  __shared__ float s1[4], s2[4];
  int lane = threadIdx.x & 63, wv = threadIdx.x >> 6;
#pragma unroll
  for (int off = 32; off >= 1; off >>= 1) {
    s += __shfl_xor(s, off); q += __shfl_xor(q, off);
  }
  if (lane == 0) { s1[wv] = s; s2[wv] = q; }
  __syncthreads();
  float ts = s1[0] + s1[1] + s1[2] + s1[3];
  float tq = s2[0] + s2[1] + s2[2] + s2[3];
  float m = ts * (1.f / 1024.f);
  float var = tq * (1.f / 1024.f) - m * m;
  *mean = m;
  *rstd = rsqrtf(var + 1e-5f);
}

// LN + exact GELU, in place on the 64 lattice-MLP rows (per-level ln params).
__global__ __launch_bounds__(256) void k_lngelu(float* __restrict__ Hh,
                                                const float* __restrict__ g,
                                                const float* __restrict__ bt)
{
  int row = blockIdx.x;
  int e = row >> 2;
  int lvl = (e < 7) ? 0 : ((e < 13) ? 1 : 2);
  int j = threadIdx.x * 4;
  float* hr = Hh + (size_t)row * DM + j;
  float4 v = *(float4*)hr;
  float s = v.x + v.y + v.z + v.w;
  float q = v.x*v.x + v.y*v.y + v.z*v.z + v.w*v.w;
  float mean, rstd;
  block_mv(s, q, &mean, &rstd);
  const float* gg = g  + lvl * DM + j;
  const float* bb = bt + lvl * DM + j;
  float t0 = (v.x - mean) * rstd * gg[0] + bb[0];
  float t1 = (v.y - mean) * rstd * gg[1] + bb[1];
  float t2 = (v.z - mean) * rstd * gg[2] + bb[2];
  float t3 = (v.w - mean) * rstd * gg[3] + bb[3];
  const float k_ = 0.70710678118654752f;
  v.x = 0.5f * t0 * (1.f + erff(t0 * k_));
  v.y = 0.5f * t1 * (1.f + erff(t1 * k_));
  v.z = 0.5f * t2 * (1.f + erff(t2 * k_));
  v.w = 0.5f * t3 * (1.f + erff(t3 * k_));
  *(float4*)hr = v;
}

// ---------------------------------------------------------------------------
// Attention: one wave per (pos, batch, head). hd=256 -> 4 dims/lane.
// ---------------------------------------------------------------------------
__global__ __launch_bounds__(64) void k_attn(const float* __restrict__ QH,
                                             const float* __restrict__ KH,
                                             const float* __restrict__ VH,
                                             float* __restrict__ OA)
{
  int bx = blockIdx.x;                  // 7*4*4 = 112
  int p = bx >> 4, b = (bx >> 2) & 3, h = bx & 3;
  int lane = threadIdx.x;
  int ne = c_ne[p];
  int qoff = (p * 4 + b) * DM + h * 256 + lane;
  float q0 = QH[qoff], q1 = QH[qoff + 64], q2 = QH[qoff + 128], q3 = QH[qoff + 192];

  float sc0 = -1e30f, sc1 = -1e30f, sc2 = -1e30f;
  int k0 = 0, k1 = 0, k2 = 0;
  {
    int E = c_posE[p][0];
    k0 = (E * 4 + b) * DM + h * 256 + lane;
    float pr = q0*KH[k0] + q1*KH[k0+64] + q2*KH[k0+128] + q3*KH[k0+192];
#pragma unroll
    for (int off = 32; off >= 1; off >>= 1) pr += __shfl_xor(pr, off);
    sc0 = pr * 0.0625f;
  }
  if (ne > 1) {
    int E = c_posE[p][1];
    k1 = (E * 4 + b) * DM + h * 256 + lane;
    float pr = q0*KH[k1] + q1*KH[k1+64] + q2*KH[k1+128] + q3*KH[k1+192];
#pragma unroll
    for (int off = 32; off >= 1; off >>= 1) pr += __shfl_xor(pr, off);
    sc1 = pr * 0.0625f;
  }
  if (ne > 2) {
    int E = c_posE[p][2];
    k2 = (E * 4 + b) * DM + h * 256 + lane;
    float pr = q0*KH[k2] + q1*KH[k2+64] + q2*KH[k2+128] + q3*KH[k2+192];
#pragma unroll
    for (int off = 32; off >= 1; off >>= 1) pr += __shfl_xor(pr, off);
    sc2 = pr * 0.0625f;
  }
  float m = fmaxf(sc0, fmaxf(sc1, sc2));
  float e0 = expf(sc0 - m);
  float e1 = (ne > 1) ? expf(sc1 - m) : 0.f;
  float e2 = (ne > 2) ? expf(sc2 - m) : 0.f;
  float inv = 1.f / (e0 + e1 + e2);
  float a0 = e0 * inv, a1 = e1 * inv, a2 = e2 * inv;
#pragma unroll
  for (int i = 0; i < 4; ++i) {
    float o = a0 * VH[k0 + i * 64];
    if (ne > 1) o += a1 * VH[k1 + i * 64];
    if (ne > 2) o += a2 * VH[k2 + i * 64];
    OA[qoff + i * 64] = o;
  }
}

// ---------------------------------------------------------------------------
// Final LN + scatter the 28 updated rows into out.
// ---------------------------------------------------------------------------
__global__ __launch_bounds__(256) void k_final(const float* __restrict__ UP,
                                               const float* __restrict__ g,
                                               const float* __restrict__ bt,
                                               float* __restrict__ out)
{
  int row = blockIdx.x;                 // 0..27
  int p = row >> 2, b = row & 3;
  int j = threadIdx.x * 4;
  const float4 v = *(const float4*)(UP + (size_t)row * DM + j);
  float s = v.x + v.y + v.z + v.w;
  float q = v.x*v.x + v.y*v.y + v.z*v.z + v.w*v.w;
  float mean, rstd;
  block_mv(s, q, &mean, &rstd);
  const float* gg = g + j;
  const float* bb = bt + j;
  float4 o;
  o.x = (v.x - mean) * rstd * gg[0] + bb[0];
  o.y = (v.y - mean) * rstd * gg[1] + bb[1];
  o.z = (v.z - mean) * rstd * gg[2] + bb[2];
  o.w = (v.w - mean) * rstd * gg[3] + bb[3];
  *(float4*)(out + ((size_t)b * SEQ + c_pos[p]) * DM + j) = o;
}

// ---------------------------------------------------------------------------
// Launch
// ---------------------------------------------------------------------------
extern "C" void kernel_launch(void* const* d_in, const int* in_sizes, int n_in,
                              void* d_out, int out_size, void* d_ws, size_t ws_size,
                              hipStream_t stream)
{
  const float* x          = (const float*)d_in[0];
  const float* lt_w1      = (const float*)d_in[1];
  const float* lt_b1      = (const float*)d_in[2];
  const float* lt_ln_g    = (const float*)d_in[3];
  const float* lt_ln_b    = (const float*)d_in[4];
  const float* lt_w2      = (const float*)d_in[5];
  const float* lt_b2      = (const float*)d_in[6];
  const float* attn_in_w  = (const float*)d_in[7];
  const float* attn_in_b  = (const float*)d_in[8];
  const float* attn_out_w = (const float*)d_in[9];
  const float* attn_out_b = (const float*)d_in[10];
  const float* fus_w      = (const float*)d_in[11];
  const float* fus_b      = (const float*)d_in[12];
  const float* fus_ln_g   = (const float*)d_in[13];
  const float* fus_ln_b   = (const float*)d_in[14];
  float* out = (float*)d_out;
  float* ws  = (float*)d_ws;

  // ws layout (floats); total 524288 floats = 2 MB
  float* F   = ws;                 // 64 rows x 1024
  float* Hh  = ws + 65536;         // 64 x 1024
  float* KV  = ws + 131072;        // 64 x 1024
  float* QIN = ws + 196608;        // 32 x 1024 (28 valid)
  float* QH  = ws + 229376;        // 32 x 1024
  float* KH  = ws + 262144;        // 64 x 1024
  float* VH  = ws + 327680;        // 64 x 1024
  float* OA  = ws + 393216;        // 32 x 1024
  float* CB  = ws + 425984;        // 32 x 2048 ([o | q])
  float* UP  = ws + 491520;        // 32 x 1024

  const long n4 = (long)out_size / 4;   // float4 count (33554432/4)
  k_copy<<<2048, 256, 0, stream>>>((const float4*)x, (float4*)out, n4);
  k_feats<<<92, 256, 0, stream>>>(x, F, QIN, CB);
  k_mm_lat<<<dim3(64, 2, 3), 256, 0, stream>>>(F, lt_w1, lt_b1, Hh);
  k_lngelu<<<64, 256, 0, stream>>>(Hh, lt_ln_g, lt_ln_b);
  k_mm_lat<<<dim3(64, 2, 3), 256, 0, stream>>>(Hh, lt_w2, lt_b2, KV);
  k_qkv<<<dim3(64, 4, 3), 256, 0, stream>>>(QIN, KV, attn_in_w, attn_in_b, QH, KH, VH);
  k_attn<<<112, 64, 0, stream>>>(QH, KH, VH, OA);
  k_gemm<<<dim3(64, 2), 256, 0, stream>>>(OA, attn_out_w, attn_out_b, CB, 28, 1024, 2048);
  k_gemm<<<dim3(64, 2), 256, 0, stream>>>(CB, fus_w, fus_b, UP, 28, 2048, 1024);
  k_final<<<28, 256, 0, stream>>>(UP, fus_ln_g, fus_ln_b, out);
}